// Round 6
// baseline (29.461 us; speedup 1.0000x reference)
//
#include <hip/hip_runtime.h>
#include <math.h>

// ---------------------------------------------------------------------------
// N-pair Gaussian mixture log-likelihood, factorized form:
//   arg_ij(x) = g_i(x) + g_j(x) + c_ij,  g_i(x) = -0.5 x'prec_i x + x'rhs_i
//   pdf(x)    = u' E u,  u_i = exp(g_i(x)),  E_ij = exp(c_ij + 64 ln2)  [scaled]
//   out       = mean_n( log pdf_n ) + log z_last   (scale folded into Kconst)
// Three kernels: setup (1 block), main (1 pt/thread, LDS-staged constants,
// ~full occupancy), final (1 block). No atomics, no fences -> deterministic.
// ---------------------------------------------------------------------------

#define LOG2E_F 1.4426950408889634f
#define LN2_F   0.6931471805599453f
#define LN2PI_F 1.8378770664093453f   // ln(2*pi)

// ws layout (float offsets) -- COEF and ES contiguous so main stages [0,904)
#define WS_COEF 0      // 16 rows * 48: per d {lin_d, Q_dd..Q_d7} *log2e; 44 used
#define WS_ES   768    // 136 packed lower-tri pair weights: diag=E'_ii, off=2E'_ij
#define WS_NSC  904    // total staged floats
#define WS_K    960    // Kconst = log z_last - 64 ln2
#define WS_PART 1024   // per-block partial sums (nb <= ~2048)

__device__ __forceinline__ float fexp2(float x) {
#if __has_builtin(__builtin_amdgcn_exp2f)
  return __builtin_amdgcn_exp2f(x);
#else
  return exp2f(x);
#endif
}
__device__ __forceinline__ float flog2(float x) {
#if __has_builtin(__builtin_amdgcn_logf)
  return __builtin_amdgcn_logf(x);
#else
  return log2f(x);
#endif
}

// Cholesky: A = C C^T (lower). Only lower triangle of A read. Fully unrolled.
__device__ __forceinline__ void chol8(const float (*A)[8], float (*C)[8]) {
  #pragma unroll
  for (int d = 0; d < 8; ++d) {
    float s = A[d][d];
    #pragma unroll
    for (int m = 0; m < 8; ++m) if (m < d) s -= C[d][m] * C[d][m];
    float cd = sqrtf(s);
    C[d][d] = cd;
    float inv = 1.f / cd;
    #pragma unroll
    for (int e = 0; e < 8; ++e) if (e > d) {
      float t = A[e][d];
      #pragma unroll
      for (int m = 0; m < 8; ++m) if (m < d) t -= C[e][m] * C[d][m];
      C[e][d] = t * inv;
    }
  }
}

// ---------------------------------------------------------------------------
// Kernel A: all setup in one block.
//  phase 1 (threads 0-15): prec_k = inv(tril(L)tril(L)'+I), rhs_k -> LDS
//  phase 2 (all 256):      pair constants -> coef rows, packed symmetric E', K
// ---------------------------------------------------------------------------
__global__ __launch_bounds__(256) void gm_setup(const float* __restrict__ mu,
                                                const float* __restrict__ L,
                                                const float* __restrict__ wts,
                                                float* __restrict__ ws) {
  __shared__ float sp[16][72];   // prec[64] + rhs[8] per component
  int tid = threadIdx.x;
  if (tid < 16) {
    int k = tid;
    float Lt[8][8];
    #pragma unroll
    for (int d = 0; d < 8; ++d)
      #pragma unroll
      for (int e = 0; e < 8; ++e)
        Lt[d][e] = (e <= d) ? L[k * 64 + d * 8 + e] : 0.f;
    float A[8][8];
    #pragma unroll
    for (int d = 0; d < 8; ++d)
      #pragma unroll
      for (int e = 0; e <= d; ++e) {
        float s = (d == e) ? 1.f : 0.f;
        #pragma unroll
        for (int m = 0; m < 8; ++m) s += Lt[d][m] * Lt[e][m];
        A[d][e] = s;
        A[e][d] = s;
      }
    float C[8][8];
    chol8(A, C);
    float Ci[8][8];
    #pragma unroll
    for (int d = 0; d < 8; ++d) Ci[d][d] = 1.f / C[d][d];
    #pragma unroll
    for (int e = 0; e < 8; ++e)
      #pragma unroll
      for (int d = 0; d < 8; ++d) if (d > e) {
        float s = 0.f;
        #pragma unroll
        for (int m = 0; m < 8; ++m) if (m >= e && m < d) s += C[d][m] * Ci[m][e];
        Ci[d][e] = -s * Ci[d][d];
      }
    #pragma unroll
    for (int a = 0; a < 8; ++a)
      #pragma unroll
      for (int b = 0; b < 8; ++b) {
        float s = 0.f;
        #pragma unroll
        for (int m = 0; m < 8; ++m) if (m >= a && m >= b) s += Ci[m][a] * Ci[m][b];
        sp[k][a * 8 + b] = s;
      }
    #pragma unroll
    for (int d = 0; d < 8; ++d) {
      float s = 0.f;
      #pragma unroll
      for (int e = 0; e < 8; ++e) s += sp[k][d * 8 + e] * mu[k * 8 + e];
      sp[k][64 + d] = s;
    }
  }
  __syncthreads();

  int p = tid;
  int i = p >> 4, j = p & 15;
  const float* pi = sp[i];
  const float* pj = sp[j];
  float P[8][8], rp[8];
  #pragma unroll
  for (int d = 0; d < 8; ++d) {
    #pragma unroll
    for (int e = 0; e < 8; ++e) P[d][e] = pi[d * 8 + e] + pj[d * 8 + e];
    rp[d] = pi[64 + d] + pj[64 + d];
  }
  float U[8][8];
  chol8(P, U);
  float logdet = 0.f;
  #pragma unroll
  for (int d = 0; d < 8; ++d) logdet += logf(U[d][d]);
  logdet *= 2.f;
  float zf[8];
  #pragma unroll
  for (int d = 0; d < 8; ++d) {
    float s = rp[d];
    #pragma unroll
    for (int m = 0; m < 8; ++m) if (m < d) s -= U[d][m] * zf[m];
    zf[d] = s / U[d][d];
  }
  float y[8];
  #pragma unroll
  for (int dd = 7; dd >= 0; --dd) {
    float s = zf[dd];
    #pragma unroll
    for (int m = 0; m < 8; ++m) if (m > dd) s -= U[m][dd] * y[m];
    y[dd] = s / U[dd][dd];
  }
  float muPmu = 0.f;
  #pragma unroll
  for (int d = 0; d < 8; ++d) muPmu += rp[d] * y[d];
  // c'_ij = -0.5 mu'Pmu + 0.5 log det P - 32 ln(2pi) + ln w_i + ln w_j + 64 ln2
  float c = -0.5f * muPmu + 0.5f * logdet - 32.f * LN2PI_F
          + logf(wts[i]) + logf(wts[j]) + 64.f * LN2_F;
  float Ev = expf(c);
  if (j <= i)   // packed lower triangle; symmetry factor 2 folded off-diagonal
    ws[WS_ES + i * (i + 1) / 2 + j] = (i == j) ? Ev : 2.f * Ev;
  if (i == j) { // main-loop coefficient row, interleaved {lin_d, Q_dd..Q_d7}
    float* c0 = ws + WS_COEF + i * 48;
    int q = 0;
    #pragma unroll
    for (int d = 0; d < 8; ++d) {
      c0[q++] = pi[64 + d] * LOG2E_F;                 // lin_d
      #pragma unroll
      for (int e = d; e < 8; ++e) {
        float v = (d == e) ? -0.5f * pi[d * 8 + e] : -pi[d * 8 + e];
        c0[q++] = v * LOG2E_F;                        // Q_de
      }
    }
    c0[44] = 0.f; c0[45] = 0.f; c0[46] = 0.f; c0[47] = 0.f;
  }
  if (p == 255) ws[WS_K] = 0.5f * logdet - 32.f * LN2PI_F - 64.f * LN2_F;
}

// ---------------------------------------------------------------------------
// Kernel B: main N-loop, ONE point per thread (grid ~= co-resident capacity:
// 1954 blocks ~ 7.6 blocks/CU ~ 30 waves/CU). Constants staged in LDS once
// per block; inner loops read them via conflict-free ds_read broadcasts.
// ---------------------------------------------------------------------------
__global__ __launch_bounds__(256) void gm_main(const float* __restrict__ X,
                                               const float* __restrict__ cf,
                                               float* __restrict__ partials,
                                               int N) {
  __shared__ float sc[WS_NSC];   // [0,768) coef rows; [768,904) packed E
  for (int t = threadIdx.x; t < WS_NSC; t += 256) sc[t] = cf[t];

  const int gid = blockIdx.x * 256 + threadIdx.x;
  const bool act = gid < N;
  const int src = act ? gid : 0;            // clamp: X[0..7] is valid memory
  const float4* Xv = reinterpret_cast<const float4*>(X) + (size_t)src * 2;
  float4 a = Xv[0], b = Xv[1];              // issued before the barrier
  __syncthreads();                          // staging complete
  float xs[8] = {a.x, a.y, a.z, a.w, b.x, b.y, b.z, b.w};

  // u[i] = exp(g_i(x)) with log2e pre-folded into coefficients
  float u[16];
  #pragma unroll
  for (int i = 0; i < 16; ++i) {
    const float* c = sc + i * 48;
    float g = 0.f;
    int q = 0;
    #pragma unroll
    for (int d = 0; d < 8; ++d) {
      float r = c[q++];                     // lin_d
      #pragma unroll
      for (int e = d; e < 8; ++e) r = fmaf(c[q++], xs[e], r);
      g = fmaf(xs[d], r, g);
    }
    u[i] = fexp2(g);
  }

  // pdf = sum_i u_i * ( sum_{j<i} 2E_ij u_j + E_ii u_i )   [E symmetric]
  float pdf = 0.f;
  #pragma unroll
  for (int i = 0; i < 16; ++i) {
    const float* e = sc + WS_ES + (i * (i + 1)) / 2;
    float s0 = 0.f, s1 = 0.f;
    #pragma unroll
    for (int j = 0; j + 1 <= i; j += 2) {
      s0 = fmaf(e[j + 0], u[j + 0], s0);
      s1 = fmaf(e[j + 1], u[j + 1], s1);
    }
    if (!(i & 1)) s0 = fmaf(e[i], u[i], s0);  // odd count: last element
    pdf = fmaf(u[i], s0 + s1, pdf);
  }
  float lsum = act ? flog2(pdf) : 0.f;

  // deterministic block reduction of sum(log2 pdf)
  #pragma unroll
  for (int off = 32; off > 0; off >>= 1) lsum += __shfl_down(lsum, off, 64);
  __shared__ float wsum[4];
  int lane = threadIdx.x & 63, wid = threadIdx.x >> 6;
  if (lane == 0) wsum[wid] = lsum;
  __syncthreads();
  if (threadIdx.x == 0)
    partials[blockIdx.x] = (wsum[0] + wsum[1]) + (wsum[2] + wsum[3]);
}

// ---------------------------------------------------------------------------
// Kernel C: deterministic final reduction (fixed-order strided + tree)
// ---------------------------------------------------------------------------
__global__ __launch_bounds__(256) void gm_final(const float* __restrict__ ws,
                                                float* __restrict__ out,
                                                int nb, float invN) {
  const float* partials = ws + WS_PART;
  float s = 0.f;
  for (int t = threadIdx.x; t < nb; t += 256) s += partials[t];
  #pragma unroll
  for (int off = 32; off > 0; off >>= 1) s += __shfl_down(s, off, 64);
  __shared__ float wsum[4];
  int lane = threadIdx.x & 63, wid = threadIdx.x >> 6;
  if (lane == 0) wsum[wid] = s;
  __syncthreads();
  if (threadIdx.x == 0) {
    float tot = (wsum[0] + wsum[1]) + (wsum[2] + wsum[3]);
    // mean(ln pdf_true) + ln z_last = ln2 * mean(log2 pdf_scaled) + Kconst
    out[0] = tot * LN2_F * invN + ws[WS_K];
  }
}

extern "C" void kernel_launch(void* const* d_in, const int* in_sizes, int n_in,
                              void* d_out, int out_size, void* d_ws, size_t ws_size,
                              hipStream_t stream) {
  const float* X = (const float*)d_in[0];
  const float* mu = (const float*)d_in[1];
  const float* L = (const float*)d_in[2];
  const float* wts = (const float*)d_in[3];
  // d_in[4] ("it") is unused by the reference math.
  float* ws = (float*)d_ws;
  float* out = (float*)d_out;
  int N = in_sizes[0] / 8;
  int nb = (N + 255) / 256;              // 1 point per thread, 256 threads
  gm_setup<<<1, 256, 0, stream>>>(mu, L, wts, ws);
  gm_main<<<nb, 256, 0, stream>>>(X, ws, ws + WS_PART, N);
  gm_final<<<1, 256, 0, stream>>>(ws, out, nb, 1.0f / (float)N);
}

// Round 7
// 24.034 us; speedup vs baseline: 1.2258x; 1.2258x over previous
//
#include <hip/hip_runtime.h>
#include <math.h>

// ---------------------------------------------------------------------------
// N-pair Gaussian mixture log-likelihood, factorized form:
//   arg_ij(x) = g_i(x) + g_j(x) + c_ij,  g_i(x) = -0.5 x'prec_i x + x'rhs_i
//   pdf(x)    = u' E u,  u_i = exp(g_i(x)),  E_ij = exp(c_ij + 64 ln2)  [scaled]
//   out       = mean_n( log pdf_n ) + log z_last   (scale folded into Kconst)
// Three kernels: setup (1 block), main (4 pts/thread, LDS constants read as
// float4 / ds_read_b128), final (1 block). No atomics -> deterministic.
// ---------------------------------------------------------------------------

#define LOG2E_F 1.4426950408889634f
#define LN2_F   0.6931471805599453f
#define LN2PI_F 1.8378770664093453f   // ln(2*pi)

// ws layout (float offsets). Staged region = [0,1024) = 256 float4.
#define WS_COEF 0      // 16 rows * 48: per d {lin_d, Q_dd..Q_d7} *log2e; 44 used
#define WS_ES   768    // 160: packed lower-tri E rows, each padded to 16B
#define WS_K    1024   // Kconst = log z_last - 64 ln2  (outside staged region)
#define WS_PART 1088   // per-block partial sums

// Padded-packed E row offsets (floats) and lengths (float4)
__device__ const int EOFF_D[16]  = {0,4,8,12,16,24,32,40,48,60,72,84,96,112,128,144};
__device__ const int ELEN4_D[16] = {1,1,1,1,2,2,2,2,3,3,3,3,4,4,4,4};

__device__ __forceinline__ float fexp2(float x) {
#if __has_builtin(__builtin_amdgcn_exp2f)
  return __builtin_amdgcn_exp2f(x);
#else
  return exp2f(x);
#endif
}
__device__ __forceinline__ float flog2(float x) {
#if __has_builtin(__builtin_amdgcn_logf)
  return __builtin_amdgcn_logf(x);
#else
  return log2f(x);
#endif
}

// Cholesky: A = C C^T (lower). Only lower triangle of A read. Fully unrolled.
__device__ __forceinline__ void chol8(const float (*A)[8], float (*C)[8]) {
  #pragma unroll
  for (int d = 0; d < 8; ++d) {
    float s = A[d][d];
    #pragma unroll
    for (int m = 0; m < 8; ++m) if (m < d) s -= C[d][m] * C[d][m];
    float cd = sqrtf(s);
    C[d][d] = cd;
    float inv = 1.f / cd;
    #pragma unroll
    for (int e = 0; e < 8; ++e) if (e > d) {
      float t = A[e][d];
      #pragma unroll
      for (int m = 0; m < 8; ++m) if (m < d) t -= C[e][m] * C[d][m];
      C[e][d] = t * inv;
    }
  }
}

// ---------------------------------------------------------------------------
// Kernel A: all setup in one block.
// ---------------------------------------------------------------------------
__global__ __launch_bounds__(256) void gm_setup(const float* __restrict__ mu,
                                                const float* __restrict__ L,
                                                const float* __restrict__ wts,
                                                float* __restrict__ ws) {
  __shared__ float sp[16][72];   // prec[64] + rhs[8] per component
  int tid = threadIdx.x;
  ws[WS_ES - 768 + 768 + tid] = 0.f;   // zero [768,1024): E pads + tail
  if (tid < 16) {
    int k = tid;
    float Lt[8][8];
    #pragma unroll
    for (int d = 0; d < 8; ++d)
      #pragma unroll
      for (int e = 0; e < 8; ++e)
        Lt[d][e] = (e <= d) ? L[k * 64 + d * 8 + e] : 0.f;
    float A[8][8];
    #pragma unroll
    for (int d = 0; d < 8; ++d)
      #pragma unroll
      for (int e = 0; e <= d; ++e) {
        float s = (d == e) ? 1.f : 0.f;
        #pragma unroll
        for (int m = 0; m < 8; ++m) s += Lt[d][m] * Lt[e][m];
        A[d][e] = s;
        A[e][d] = s;
      }
    float C[8][8];
    chol8(A, C);
    float Ci[8][8];
    #pragma unroll
    for (int d = 0; d < 8; ++d) Ci[d][d] = 1.f / C[d][d];
    #pragma unroll
    for (int e = 0; e < 8; ++e)
      #pragma unroll
      for (int d = 0; d < 8; ++d) if (d > e) {
        float s = 0.f;
        #pragma unroll
        for (int m = 0; m < 8; ++m) if (m >= e && m < d) s += C[d][m] * Ci[m][e];
        Ci[d][e] = -s * Ci[d][d];
      }
    #pragma unroll
    for (int a = 0; a < 8; ++a)
      #pragma unroll
      for (int b = 0; b < 8; ++b) {
        float s = 0.f;
        #pragma unroll
        for (int m = 0; m < 8; ++m) if (m >= a && m >= b) s += Ci[m][a] * Ci[m][b];
        sp[k][a * 8 + b] = s;
      }
    #pragma unroll
    for (int d = 0; d < 8; ++d) {
      float s = 0.f;
      #pragma unroll
      for (int e = 0; e < 8; ++e) s += sp[k][d * 8 + e] * mu[k * 8 + e];
      sp[k][64 + d] = s;
    }
  }
  __syncthreads();   // sp ready; zeroing of [768,1024) visible block-wide

  int p = tid;
  int i = p >> 4, j = p & 15;
  const float* pi = sp[i];
  const float* pj = sp[j];
  float P[8][8], rp[8];
  #pragma unroll
  for (int d = 0; d < 8; ++d) {
    #pragma unroll
    for (int e = 0; e < 8; ++e) P[d][e] = pi[d * 8 + e] + pj[d * 8 + e];
    rp[d] = pi[64 + d] + pj[64 + d];
  }
  float U[8][8];
  chol8(P, U);
  float logdet = 0.f;
  #pragma unroll
  for (int d = 0; d < 8; ++d) logdet += logf(U[d][d]);
  logdet *= 2.f;
  float zf[8];
  #pragma unroll
  for (int d = 0; d < 8; ++d) {
    float s = rp[d];
    #pragma unroll
    for (int m = 0; m < 8; ++m) if (m < d) s -= U[d][m] * zf[m];
    zf[d] = s / U[d][d];
  }
  float y[8];
  #pragma unroll
  for (int dd = 7; dd >= 0; --dd) {
    float s = zf[dd];
    #pragma unroll
    for (int m = 0; m < 8; ++m) if (m > dd) s -= U[m][dd] * y[m];
    y[dd] = s / U[dd][dd];
  }
  float muPmu = 0.f;
  #pragma unroll
  for (int d = 0; d < 8; ++d) muPmu += rp[d] * y[d];
  // c'_ij = -0.5 mu'Pmu + 0.5 log det P - 32 ln(2pi) + ln w_i + ln w_j + 64 ln2
  float c = -0.5f * muPmu + 0.5f * logdet - 32.f * LN2PI_F
          + logf(wts[i]) + logf(wts[j]) + 64.f * LN2_F;
  float Ev = expf(c);
  if (j <= i)   // padded-packed lower triangle; factor 2 folded off-diagonal
    ws[WS_ES + EOFF_D[i] + j] = (i == j) ? Ev : 2.f * Ev;
  if (i == j) { // main-loop coefficient row, interleaved {lin_d, Q_dd..Q_d7}
    float* c0 = ws + WS_COEF + i * 48;
    int q = 0;
    #pragma unroll
    for (int d = 0; d < 8; ++d) {
      c0[q++] = pi[64 + d] * LOG2E_F;                 // lin_d
      #pragma unroll
      for (int e = d; e < 8; ++e) {
        float v = (d == e) ? -0.5f * pi[d * 8 + e] : -pi[d * 8 + e];
        c0[q++] = v * LOG2E_F;                        // Q_de
      }
    }
    c0[44] = 0.f; c0[45] = 0.f; c0[46] = 0.f; c0[47] = 0.f;
  }
  if (p == 255) ws[WS_K] = 0.5f * logdet - 32.f * LN2PI_F - 64.f * LN2_F;
}

// ---------------------------------------------------------------------------
// Kernel B: main N-loop, 4 points per thread. 1024-float constant table is
// staged into LDS (one float4 per thread) and read back exclusively as
// float4 (ds_read_b128 broadcasts): 176 coef + 40 E reads per point-set,
// vs 840 scalar reads before -> LDS issue no longer the bottleneck.
// ---------------------------------------------------------------------------
__global__ __launch_bounds__(256) void gm_main(const float* __restrict__ X,
                                               const float* __restrict__ cf,
                                               float* __restrict__ partials,
                                               int N) {
  __shared__ float sc[1024];   // [0,768) coef rows; [768,928) padded E; pad
  {
    const float4* cf4 = reinterpret_cast<const float4*>(cf);
    reinterpret_cast<float4*>(sc)[threadIdx.x] = cf4[threadIdx.x];
  }

  const int t = threadIdx.x;
  const int base = blockIdx.x * 1024 + t;
  float xs[4][8];
  bool act[4];
  #pragma unroll
  for (int g = 0; g < 4; ++g) {
    int gid = base + g * 256;
    act[g] = gid < N;
    int src = act[g] ? gid : 0;            // clamp: X[0..7] is valid memory
    const float4* Xv = reinterpret_cast<const float4*>(X) + (size_t)src * 2;
    float4 a = Xv[0], b = Xv[1];
    xs[g][0] = a.x; xs[g][1] = a.y; xs[g][2] = a.z; xs[g][3] = a.w;
    xs[g][4] = b.x; xs[g][5] = b.y; xs[g][6] = b.z; xs[g][7] = b.w;
  }
  __syncthreads();                          // staging complete

  // u[g][i] = exp(g_i(x_g)) with log2e pre-folded into coefficients
  float u[4][16];
  #pragma unroll
  for (int i = 0; i < 16; ++i) {
    const float4* c4 = reinterpret_cast<const float4*>(sc + i * 48);
    float cr[44];
    #pragma unroll
    for (int v = 0; v < 11; ++v) {          // 11x ds_read_b128
      float4 w = c4[v];
      cr[4 * v + 0] = w.x; cr[4 * v + 1] = w.y;
      cr[4 * v + 2] = w.z; cr[4 * v + 3] = w.w;
    }
    float g0 = 0.f, g1 = 0.f, g2 = 0.f, g3 = 0.f;
    int q = 0;
    #pragma unroll
    for (int d = 0; d < 8; ++d) {
      float lc = cr[q++];
      float r0 = lc, r1 = lc, r2 = lc, r3 = lc;   // lin_d
      #pragma unroll
      for (int e = d; e < 8; ++e) {
        float cc = cr[q++];
        r0 = fmaf(cc, xs[0][e], r0);
        r1 = fmaf(cc, xs[1][e], r1);
        r2 = fmaf(cc, xs[2][e], r2);
        r3 = fmaf(cc, xs[3][e], r3);
      }
      g0 = fmaf(xs[0][d], r0, g0);
      g1 = fmaf(xs[1][d], r1, g1);
      g2 = fmaf(xs[2][d], r2, g2);
      g3 = fmaf(xs[3][d], r3, g3);
    }
    u[0][i] = fexp2(g0);
    u[1][i] = fexp2(g1);
    u[2][i] = fexp2(g2);
    u[3][i] = fexp2(g3);
  }

  // pdf = sum_i u_i * (padded row_i . u)   [diag=E'_ii, off=2E'_ij, pads=0]
  constexpr int EOFF[16]  = {0,4,8,12,16,24,32,40,48,60,72,84,96,112,128,144};
  constexpr int ELEN4[16] = {1,1,1,1,2,2,2,2,3,3,3,3,4,4,4,4};
  const float4* es4 = reinterpret_cast<const float4*>(sc + 768);
  float p0 = 0.f, p1 = 0.f, p2 = 0.f, p3 = 0.f;
  #pragma unroll
  for (int i = 0; i < 16; ++i) {
    float s0 = 0.f, s1 = 0.f, s2 = 0.f, s3 = 0.f;
    #pragma unroll
    for (int q4 = 0; q4 < ELEN4[i]; ++q4) {  // ds_read_b128 per 4 E entries
      float4 ev = es4[EOFF[i] / 4 + q4];
      const int j = q4 * 4;
      s0 = fmaf(ev.x, u[0][j + 0], s0); s0 = fmaf(ev.y, u[0][j + 1], s0);
      s0 = fmaf(ev.z, u[0][j + 2], s0); s0 = fmaf(ev.w, u[0][j + 3], s0);
      s1 = fmaf(ev.x, u[1][j + 0], s1); s1 = fmaf(ev.y, u[1][j + 1], s1);
      s1 = fmaf(ev.z, u[1][j + 2], s1); s1 = fmaf(ev.w, u[1][j + 3], s1);
      s2 = fmaf(ev.x, u[2][j + 0], s2); s2 = fmaf(ev.y, u[2][j + 1], s2);
      s2 = fmaf(ev.z, u[2][j + 2], s2); s2 = fmaf(ev.w, u[2][j + 3], s2);
      s3 = fmaf(ev.x, u[3][j + 0], s3); s3 = fmaf(ev.y, u[3][j + 1], s3);
      s3 = fmaf(ev.z, u[3][j + 2], s3); s3 = fmaf(ev.w, u[3][j + 3], s3);
    }
    p0 = fmaf(u[0][i], s0, p0);
    p1 = fmaf(u[1][i], s1, p1);
    p2 = fmaf(u[2][i], s2, p2);
    p3 = fmaf(u[3][i], s3, p3);
  }
  float lsum = 0.f;
  if (act[0]) lsum += flog2(p0);
  if (act[1]) lsum += flog2(p1);
  if (act[2]) lsum += flog2(p2);
  if (act[3]) lsum += flog2(p3);

  // deterministic block reduction of sum(log2 pdf)
  #pragma unroll
  for (int off = 32; off > 0; off >>= 1) lsum += __shfl_down(lsum, off, 64);
  __shared__ float wsum[4];
  int lane = threadIdx.x & 63, wid = threadIdx.x >> 6;
  if (lane == 0) wsum[wid] = lsum;
  __syncthreads();
  if (threadIdx.x == 0)
    partials[blockIdx.x] = (wsum[0] + wsum[1]) + (wsum[2] + wsum[3]);
}

// ---------------------------------------------------------------------------
// Kernel C: deterministic final reduction (fixed-order strided + tree)
// ---------------------------------------------------------------------------
__global__ __launch_bounds__(256) void gm_final(const float* __restrict__ ws,
                                                float* __restrict__ out,
                                                int nb, float invN) {
  const float* partials = ws + WS_PART;
  float s = 0.f;
  for (int t = threadIdx.x; t < nb; t += 256) s += partials[t];
  #pragma unroll
  for (int off = 32; off > 0; off >>= 1) s += __shfl_down(s, off, 64);
  __shared__ float wsum[4];
  int lane = threadIdx.x & 63, wid = threadIdx.x >> 6;
  if (lane == 0) wsum[wid] = s;
  __syncthreads();
  if (threadIdx.x == 0) {
    float tot = (wsum[0] + wsum[1]) + (wsum[2] + wsum[3]);
    // mean(ln pdf_true) + ln z_last = ln2 * mean(log2 pdf_scaled) + Kconst
    out[0] = tot * LN2_F * invN + ws[WS_K];
  }
}

extern "C" void kernel_launch(void* const* d_in, const int* in_sizes, int n_in,
                              void* d_out, int out_size, void* d_ws, size_t ws_size,
                              hipStream_t stream) {
  const float* X = (const float*)d_in[0];
  const float* mu = (const float*)d_in[1];
  const float* L = (const float*)d_in[2];
  const float* wts = (const float*)d_in[3];
  // d_in[4] ("it") is unused by the reference math.
  float* ws = (float*)d_ws;
  float* out = (float*)d_out;
  int N = in_sizes[0] / 8;
  int nb = (N + 1023) / 1024;            // 4 points per thread, 256 threads
  gm_setup<<<1, 256, 0, stream>>>(mu, L, wts, ws);
  gm_main<<<nb, 256, 0, stream>>>(X, ws, ws + WS_PART, N);
  gm_final<<<1, 256, 0, stream>>>(ws, out, nb, 1.0f / (float)N);
}